// Round 3
// baseline (828.445 us; speedup 1.0000x reference)
//
#include <hip/hip_runtime.h>
#include <hip/hip_bf16.h>
#include <stdint.h>

// Problem constants (compile-time; shapes fixed by setup_inputs()).
#define M_ROWS 4096      // batch rows of x
#define IN_F   4096      // K
#define OUT_F  11008     // N
#define N_GROUPS 32      // IN_F / 128
#define ALPHA  0.05f

typedef __bf16 bf16;
typedef __bf16 bf16x8 __attribute__((ext_vector_type(8)));
typedef float  floatx16 __attribute__((ext_vector_type(16)));

// async global->LDS, 16B per lane; LDS dest = wave-uniform base + lane*16
__device__ __forceinline__ void async_copy16(const void* g, void* l) {
  __builtin_amdgcn_global_load_lds(
      (const __attribute__((address_space(1))) void*)g,
      (__attribute__((address_space(3))) void*)l, 16, 0, 0);
}

// ---------------------------------------------------------------------------
// Phase 1 (fused): grid-strided, 2048 blocks. Streaming floor ~110 us
// (q 180MB + noise 180MB + x 67MB in, wn 90MB + xb 34MB out @ ~5.5 TB/s).
// Round-2 evidence: residual (total - gemm) identical between the split
// one-shot version and this one -> prep is at/near its BW floor; the rest of
// the residual (~300 us) is harness reset dispatches. Unchanged this round.
// ---------------------------------------------------------------------------
__global__ __launch_bounds__(256) void prep_kernel(
    const float* __restrict__ x, const int* __restrict__ q,
    const float* __restrict__ scales, const float* __restrict__ zeros,
    const float* __restrict__ noise, bf16* __restrict__ wn,
    bf16* __restrict__ xb) {
  const int W_CH = OUT_F * (IN_F >> 3);              // 5,636,096 weight chunks
  const int T_CH = W_CH + (M_ROWS * (IN_F >> 3));    // + 2,097,152 x chunks
  const int stride = gridDim.x * 256;
  for (int idx = blockIdx.x * 256 + threadIdx.x; idx < T_CH; idx += stride) {
    if (idx < W_CH) {
      int o = idx >> 9;                  // 512 chunks per output row
      int i = (idx & 511) << 3;          // 8-aligned -> single group
      int g = i >> 7;
      float s = scales[o * N_GROUPS + g];
      float z = zeros[o * N_GROUPS + g];
      size_t base = (size_t)o * IN_F + i;
      int4   q0 = *(const int4*)(q + base);
      int4   q1 = *(const int4*)(q + base + 4);
      float4 n0 = *(const float4*)(noise + base);
      float4 n1 = *(const float4*)(noise + base + 4);
      float qs[8] = {(float)q0.x, (float)q0.y, (float)q0.z, (float)q0.w,
                     (float)q1.x, (float)q1.y, (float)q1.z, (float)q1.w};
      float ns[8] = {n0.x, n0.y, n0.z, n0.w, n1.x, n1.y, n1.z, n1.w};
      bf16x8 outv;
#pragma unroll
      for (int j = 0; j < 8; ++j) {
        float w = (qs[j] - z) * s;
        float v = fmaf(ALPHA * fabsf(w), ns[j], w);   // w + noise*ALPHA*|w|
        outv[j] = (bf16)v;
      }
      *(bf16x8*)(wn + base) = outv;
    } else {
      size_t base = (size_t)(idx - W_CH) << 3;
      float4 a0 = *(const float4*)(x + base);
      float4 a1 = *(const float4*)(x + base + 4);
      float vs[8] = {a0.x, a0.y, a0.z, a0.w, a1.x, a1.y, a1.z, a1.w};
      bf16x8 outv;
#pragma unroll
      for (int j = 0; j < 8; ++j) outv[j] = (bf16)vs[j];
      *(bf16x8*)(xb + base) = outv;
    }
  }
}

// ---------------------------------------------------------------------------
// Phase 2: 256x256-tile 8-phase GEMM, 32x32x16 MFMA core.
//
// SWIZZLE FIX (round 3): round 2 measured 3.38e7 bank conflicts. Evidence
// triple {16x16 read: 0, linear stage write: 0, 32x32 read: conflicts} pins
// the b128 service grouping to pair lanes DELTA=16 apart (groups
// {2c,2c+1,2c+16,2c+17,2c+32,2c+33,2c+48,2c+49}); in the old layout lanes
// l and l+16 had identical physical chunk pc and bank-invariant row-pair
// offset (8 rp = 1024 B) -> systematic 2-way conflict.
//
// New layout: logical (row r, 8-elem chunk kc in 0..3) lives at elem
//   (r>>1)*64 + pc*8,  pc = (((r&1)<<2)|kc) ^ g(rp),  rp = r>>1,
//   g(rp) = (rp&7) ^ (((rp>>3)&1)<<1).
// The added bit: g(c)^g(c+8) = 2 (bit1 set) => the two rp-octets' pc-sets
// {0,1,4,5}^g(c) and {0,1,4,5}^g(c+8) are disjoint => every service group
// (which spans rp c and c+8) gets all 8 bank-groups exactly once. Verified
// exhaustively for c=0..7.
//
// Staging (gload_lds dest linear: lane ln -> phys (rp = wv*16+j*8+(ln>>3),
// pc = ln&7)): inverse layout gives pack = (ln&7)^(ln>>3)^(j<<1), so the
// j=1 sub-instr's GLOBAL source flips kc bit1 (col ^16 elems) and +16 rows;
// row parity unchanged. Read side: pc gains ^(((l31>>4)&1)<<1); mt/nt
// strides (16 rp) leave rp bit3-parity-within... (rp>>3)&1 unchanged, and
// k-half 1 remains the uniform elem ^16 (pc^2).
//
// Operand layouts (32x32x16 bf16):
//  A/B: lane l holds row/col = l&31, k = (l>>5)*8 + j  (8 bf16).
//  C/D (m74/m101-verified): col = lane&31, row = (reg&3)+8*(reg>>2)+4*(lane>>5).
// ---------------------------------------------------------------------------
__global__ __launch_bounds__(512, 2) void gemm_8ph_kernel(
    const bf16* __restrict__ A,    // [M_ROWS][IN_F]
    const bf16* __restrict__ W,    // [OUT_F][IN_F]
    const float* __restrict__ bias,
    float* __restrict__ C) {       // [M_ROWS][OUT_F]
  __shared__ bf16 lds[4 * 16384];  // 4 pair-slots x (A 8192 + B 8192) elems

  const int tid = threadIdx.x;
  const int wv = tid >> 6;          // wave 0..7
  const int ln = tid & 63;
  const int wr = wv >> 2;           // wave M row (0..1) -> rows wr*128..+128
  const int wc = wv & 3;            // wave N col (0..3) -> cols wc*64..+64

  // XCD-bijective swizzle (688 = 8*86) + m-pair supertile.
  const int orig = blockIdx.x;
  const int idx  = orig >> 3;                    // 0..85
  const int bm   = ((orig & 7) << 1) | (idx & 1);
  const int bn   = idx >> 1;
  const int mbase = bm << 8;
  const int nbase = bn << 8;

  // Staging source (per-lane pre-swizzled global address; LDS dest linear).
  const int dec    = (ln & 7) ^ (ln >> 3);
  const int rstage = wv * 32 + (ln >> 3) * 2 + (dec >> 2);  // j=0 row
  const int kcol   = (dec & 3) * 8;
  const bf16* aS0 = A + (size_t)(mbase + rstage) * IN_F + kcol;
  const bf16* aS1 = A + (size_t)(mbase + rstage + 16) * IN_F + (kcol ^ 16);
  const bf16* bS0 = W + (size_t)(nbase + rstage) * IN_F + kcol;
  const bf16* bS1 = W + (size_t)(nbase + rstage + 16) * IN_F + (kcol ^ 16);

  // Fragment ds_read offsets (elements), k-half 0; k-half 1 = ^16.
  const int l31 = ln & 31;
  const int g2  = ln >> 5;
  const int key = ((l31 >> 1) & 7) ^ (((l31 >> 4) & 1) << 1);
  const int pc  = ((((ln & 1) << 2) | g2) ^ key);
  const int aoff0 =        (wr * 64 + (l31 >> 1)) * 64 + pc * 8;  // + mt*1024
  const int boff0 = 8192 + (wc * 32 + (l31 >> 1)) * 64 + pc * 8;  // + nt*1024

  floatx16 acc[4][2] = {};

#define STAGE_A(DST, KH)                                                          \
  do {                                                                            \
    async_copy16(aS0 + (size_t)(KH) * 32, &lds[(DST) * 16384 + wv * 1024]);       \
    async_copy16(aS1 + (size_t)(KH) * 32, &lds[(DST) * 16384 + wv * 1024 + 512]); \
  } while (0)
#define STAGE_B(DST, KH)                                                          \
  do {                                                                            \
    async_copy16(bS0 + (size_t)(KH) * 32, &lds[(DST) * 16384 + 8192 + wv * 1024]);       \
    async_copy16(bS1 + (size_t)(KH) * 32, &lds[(DST) * 16384 + 8192 + wv * 1024 + 512]); \
  } while (0)

  // Prologue: stage P0,P1,P2 (12 loads). vmcnt(8) -> oldest 4 (P0) landed.
  STAGE_A(0, 0); STAGE_B(0, 0);
  STAGE_A(1, 1); STAGE_B(1, 1);
  STAGE_A(2, 2); STAGE_B(2, 2);
  asm volatile("s_waitcnt vmcnt(8)" ::: "memory");
  __builtin_amdgcn_s_barrier();

#define PAIR(SLOT, KH, DO_STAGE, TVM)                                             \
  {                                                                               \
    bf16x8 af[4], bq[2];                                                          \
    _Pragma("unroll") for (int mt = 0; mt < 4; ++mt)                              \
      af[mt] = *(const bf16x8*)&lds[(SLOT) * 16384 + aoff0 + mt * 1024];          \
    _Pragma("unroll") for (int nt = 0; nt < 2; ++nt)                              \
      bq[nt] = *(const bf16x8*)&lds[(SLOT) * 16384 + boff0 + nt * 1024];          \
    if (DO_STAGE) STAGE_A(((SLOT) + 3) & 3, (KH) + 3);                            \
    __builtin_amdgcn_s_barrier();                                                 \
    asm volatile("s_waitcnt lgkmcnt(0)" ::: "memory");                            \
    __builtin_amdgcn_s_setprio(1);                                                \
    _Pragma("unroll") for (int mt = 0; mt < 4; ++mt)                              \
      _Pragma("unroll") for (int nt = 0; nt < 2; ++nt)                            \
        acc[mt][nt] = __builtin_amdgcn_mfma_f32_32x32x16_bf16(                    \
            af[mt], bq[nt], acc[mt][nt], 0, 0, 0);                                \
    __builtin_amdgcn_s_setprio(0);                                                \
    __builtin_amdgcn_s_barrier();                                                 \
    _Pragma("unroll") for (int mt = 0; mt < 4; ++mt)                              \
      af[mt] = *(const bf16x8*)&lds[(SLOT) * 16384 + ((aoff0 ^ 16) + mt * 1024)]; \
    _Pragma("unroll") for (int nt = 0; nt < 2; ++nt)                              \
      bq[nt] = *(const bf16x8*)&lds[(SLOT) * 16384 + ((boff0 ^ 16) + nt * 1024)]; \
    if (DO_STAGE) STAGE_B(((SLOT) + 3) & 3, (KH) + 3);                            \
    __builtin_amdgcn_s_barrier();                                                 \
    asm volatile("s_waitcnt lgkmcnt(0)" ::: "memory");                            \
    __builtin_amdgcn_s_setprio(1);                                                \
    _Pragma("unroll") for (int mt = 0; mt < 4; ++mt)                              \
      _Pragma("unroll") for (int nt = 0; nt < 2; ++nt)                            \
        acc[mt][nt] = __builtin_amdgcn_mfma_f32_32x32x16_bf16(                    \
            af[mt], bq[nt], acc[mt][nt], 0, 0, 0);                                \
    __builtin_amdgcn_s_setprio(0);                                                \
    asm volatile("s_waitcnt " TVM ::: "memory");                                  \
    __builtin_amdgcn_s_barrier();                                                 \
  }

  // Main loop: 31 ring revolutions (pairs 0..123), all staging P_{n+3}.
  for (int kh = 0; kh < 124; kh += 4) {
    PAIR(0, kh + 0, true, "vmcnt(8)");
    PAIR(1, kh + 1, true, "vmcnt(8)");
    PAIR(2, kh + 2, true, "vmcnt(8)");
    PAIR(3, kh + 3, true, "vmcnt(8)");
  }
  // Tail: pair 124 still stages P_127; then drain 8 -> 4 -> 0.
  PAIR(0, 124, true,  "vmcnt(8)");
  PAIR(1, 125, false, "vmcnt(4)");
  PAIR(2, 126, false, "vmcnt(0)");
  PAIR(3, 127, false, "vmcnt(0)");

#undef PAIR
#undef STAGE_A
#undef STAGE_B

  // Epilogue. 32x32 C/D layout: col = lane&31, row = (reg&3)+8*(reg>>2)+4*g2.
#pragma unroll
  for (int nt = 0; nt < 2; ++nt) {
    int n = nbase + wc * 64 + nt * 32 + l31;
    float bv = bias[n];
#pragma unroll
    for (int mt = 0; mt < 4; ++mt) {
      int mb2 = mbase + wr * 128 + mt * 32 + 4 * g2;
#pragma unroll
      for (int r = 0; r < 16; ++r) {
        int m = mb2 + (r & 3) + 8 * (r >> 2);
        C[(size_t)m * OUT_F + n] = acc[mt][nt][r] + bv;
      }
    }
  }
}

// ---------------------------------------------------------------------------
extern "C" void kernel_launch(void* const* d_in, const int* in_sizes, int n_in,
                              void* d_out, int out_size, void* d_ws, size_t ws_size,
                              hipStream_t stream) {
  const float* x       = (const float*)d_in[0];  // [4096][4096]
  const int*   qweight = (const int*)d_in[1];    // [11008][4096]
  const float* scales  = (const float*)d_in[2];  // [11008][32]
  const float* zeros   = (const float*)d_in[3];  // [11008][32]
  const float* bias    = (const float*)d_in[4];  // [11008]
  const float* noise   = (const float*)d_in[5];  // [11008][4096]
  float* out = (float*)d_out;                    // [4096][11008]

  // Workspace layout: wn bf16 [OUT_F][IN_F] (90.2 MB), then xb bf16 (33.6 MB).
  bf16* wn = (bf16*)d_ws;
  bf16* xb = (bf16*)((char*)d_ws + (size_t)OUT_F * IN_F * sizeof(bf16));

  // Phase 1: fused dequant+noise+xcast, grid-strided at 8 blocks/CU.
  prep_kernel<<<2048, 256, 0, stream>>>(x, qweight, scales, zeros, noise, wn, xb);

  // Phase 2: 256x256-tile 8-phase bf16 MFMA GEMM (32x32x16 core).
  // Grid: (11008/256)*(4096/256) = 43*16 = 688 = 8 XCDs * 86.
  gemm_8ph_kernel<<<dim3(688), 512, 0, stream>>>(xb, wn, bias, out);
}

// Round 4
// 781.297 us; speedup vs baseline: 1.0603x; 1.0603x over previous
//
#include <hip/hip_runtime.h>
#include <hip/hip_bf16.h>
#include <stdint.h>

// Problem constants (compile-time; shapes fixed by setup_inputs()).
#define M_ROWS 4096      // batch rows of x
#define IN_F   4096      // K
#define OUT_F  11008     // N
#define N_GROUPS 32      // IN_F / 128
#define ALPHA  0.05f

typedef __bf16 bf16;
typedef __bf16 bf16x8 __attribute__((ext_vector_type(8)));
typedef float  floatx4 __attribute__((ext_vector_type(4)));

// async global->LDS, 16B per lane; LDS dest = wave-uniform base + lane*16
__device__ __forceinline__ void async_copy16(const void* g, void* l) {
  __builtin_amdgcn_global_load_lds(
      (const __attribute__((address_space(1))) void*)g,
      (__attribute__((address_space(3))) void*)l, 16, 0, 0);
}

// ---------------------------------------------------------------------------
// Phase 1 (fused): grid-strided, 2048 blocks. Streaming floor ~110 us.
// Round-2 evidence: residual (total - gemm) identical between split one-shot
// and fused grid-stride versions -> prep is at/near its BW floor; remaining
// residual is harness reset overhead. Unchanged.
// ---------------------------------------------------------------------------
__global__ __launch_bounds__(256) void prep_kernel(
    const float* __restrict__ x, const int* __restrict__ q,
    const float* __restrict__ scales, const float* __restrict__ zeros,
    const float* __restrict__ noise, bf16* __restrict__ wn,
    bf16* __restrict__ xb) {
  const int W_CH = OUT_F * (IN_F >> 3);              // 5,636,096 weight chunks
  const int T_CH = W_CH + (M_ROWS * (IN_F >> 3));    // + 2,097,152 x chunks
  const int stride = gridDim.x * 256;
  for (int idx = blockIdx.x * 256 + threadIdx.x; idx < T_CH; idx += stride) {
    if (idx < W_CH) {
      int o = idx >> 9;                  // 512 chunks per output row
      int i = (idx & 511) << 3;          // 8-aligned -> single group
      int g = i >> 7;
      float s = scales[o * N_GROUPS + g];
      float z = zeros[o * N_GROUPS + g];
      size_t base = (size_t)o * IN_F + i;
      int4   q0 = *(const int4*)(q + base);
      int4   q1 = *(const int4*)(q + base + 4);
      float4 n0 = *(const float4*)(noise + base);
      float4 n1 = *(const float4*)(noise + base + 4);
      float qs[8] = {(float)q0.x, (float)q0.y, (float)q0.z, (float)q0.w,
                     (float)q1.x, (float)q1.y, (float)q1.z, (float)q1.w};
      float ns[8] = {n0.x, n0.y, n0.z, n0.w, n1.x, n1.y, n1.z, n1.w};
      bf16x8 outv;
#pragma unroll
      for (int j = 0; j < 8; ++j) {
        float w = (qs[j] - z) * s;
        float v = fmaf(ALPHA * fabsf(w), ns[j], w);   // w + noise*ALPHA*|w|
        outv[j] = (bf16)v;
      }
      *(bf16x8*)(wn + base) = outv;
    } else {
      size_t base = (size_t)(idx - W_CH) << 3;
      float4 a0 = *(const float4*)(x + base);
      float4 a1 = *(const float4*)(x + base + 4);
      float vs[8] = {a0.x, a0.y, a0.z, a0.w, a1.x, a1.y, a1.z, a1.w};
      bf16x8 outv;
#pragma unroll
      for (int j = 0; j < 8; ++j) outv[j] = (bf16)vs[j];
      *(bf16x8*)(xb + base) = outv;
    }
  }
}

// ---------------------------------------------------------------------------
// Phase 2: 256x256-tile GEMM, 16x16x32 core (round-1 proven: 0 conflicts),
// ONE barrier per K=32 pair (round 4 change).
//
// ROUND-3 POST-MORTEM: the 32x32 core's 3.38e7 bank conflicts were invariant
// to two different derived swizzles (exactly 4 cyc/read both times) -> no
// validated conflict model; and arithmetically 32x32 reads the same LDS
// bytes with LESS MFMA pipe time (cap ~50% vs 16x16's ~60%). Reverted to the
// 16x16 core whose read pattern measured ZERO conflicts (rounds 0/1).
//
// BARRIER REDUCTION (this round's change): hazard audit of the old 4
// barriers/pair:
//  - reads (afr/bfr/afr2) touch only slot n, made ready by the PREVIOUS
//    pair-end barrier -> no intra-pair barrier needed;
//  - STAGE_A/STAGE_B write slot n+3, whose last reader (pair n-1) finished
//    before that same previous pair-end barrier -> safe anywhere in pair n;
//  - cross-wave staging visibility for slot n+1 needs exactly one
//    vmcnt(8)+s_barrier per pair boundary (queue at pair-n end =
//    P_{n+1}(4,oldest)+P_{n+2}(4)+P_{n+3}(4); FIFO retirement => vmcnt(8)
//    proves P_{n+1} landed while 8 loads stay in flight across the barrier).
// => 1 barrier/pair. ds_read->MFMA waits are left to the compiler (m97
// evidence: it emits counted lgkmcnt and can hoist the mi4-7 reads and
// stage-issues under the MFMA clusters). sched_barrier(0) after each
// pair-end barrier pins next-pair ds_reads below it (rule #18 insurance).
//
// LDS layout/swizzle (round-1, measured conflict-free): logical (row r,
// 8-elem chunk kc) at elem (r>>1)*64 + pc*8, pc = (((r&1)<<2)|kc) ^ ((r>>1)&7).
// Staging realizes it by pre-permuting each lane's GLOBAL source chunk
// (LDS dest linear, per gload_lds rules). Fragment read: lane(frow=ln&15,
// g4=ln>>4) reads rp = base + (frow>>1), kc = g4.
// ---------------------------------------------------------------------------
__global__ __launch_bounds__(512, 2) void gemm_8ph_kernel(
    const bf16* __restrict__ A,    // [M_ROWS][IN_F]
    const bf16* __restrict__ W,    // [OUT_F][IN_F]
    const float* __restrict__ bias,
    float* __restrict__ C) {       // [M_ROWS][OUT_F]
  __shared__ bf16 lds[4 * 16384];  // 4 pair-slots x (A 8192 + B 8192) elems

  const int tid = threadIdx.x;
  const int wv = tid >> 6;          // wave 0..7
  const int ln = tid & 63;
  const int wr = wv >> 2;           // wave M row (0..1) -> rows wr*128..+128
  const int wc = wv & 3;            // wave N col (0..3) -> cols wc*64..+64

  // XCD-bijective swizzle (688 = 8*86) + m-pair supertile: each XCD sweeps
  // bn with 2 resident A panels (4 MB, L2-fits); all XCDs share B via L3.
  const int orig = blockIdx.x;
  const int idx  = orig >> 3;                    // 0..85
  const int bm   = ((orig & 7) << 1) | (idx & 1);
  const int bn   = idx >> 1;
  const int mbase = bm << 8;
  const int nbase = bn << 8;

  // Staging source (per-lane pre-swizzled global address; LDS dest linear).
  const int dec    = (ln & 7) ^ (ln >> 3);
  const int rstage = wv * 32 + (ln >> 3) * 2 + (dec >> 2);  // j=0 row; j=1 +16
  const int kcol   = (dec & 3) * 8;
  const bf16* aS = A + (size_t)(mbase + rstage) * IN_F + kcol;
  const bf16* bS = W + (size_t)(nbase + rstage) * IN_F + kcol;

  // Fragment ds_read offsets (elements).
  const int frow = ln & 15;
  const int g4   = ln >> 4;
  const int pc   = (((frow & 1) << 2) | g4) ^ (frow >> 1);
  const int aoff =        (wr * 64 + (frow >> 1)) * 64 + pc * 8;  // + mi*512
  const int boff = 8192 + (wc * 32 + (frow >> 1)) * 64 + pc * 8;  // + ni*512

  floatx4 acc[8][4] = {};

#define STAGE_A(DST, KH)                                                          \
  do {                                                                            \
    async_copy16(aS + (size_t)(KH) * 32,             &lds[(DST) * 16384 + wv * 1024]);        \
    async_copy16(aS + (size_t)(KH) * 32 + 16 * IN_F, &lds[(DST) * 16384 + wv * 1024 + 512]);  \
  } while (0)
#define STAGE_B(DST, KH)                                                          \
  do {                                                                            \
    async_copy16(bS + (size_t)(KH) * 32,             &lds[(DST) * 16384 + 8192 + wv * 1024]);       \
    async_copy16(bS + (size_t)(KH) * 32 + 16 * IN_F, &lds[(DST) * 16384 + 8192 + wv * 1024 + 512]); \
  } while (0)

  // Prologue: stage P0,P1,P2 (12 loads). vmcnt(8) -> oldest 4 (P0) landed.
  STAGE_A(0, 0); STAGE_B(0, 0);
  STAGE_A(1, 1); STAGE_B(1, 1);
  STAGE_A(2, 2); STAGE_B(2, 2);
  asm volatile("s_waitcnt vmcnt(8)" ::: "memory");
  __builtin_amdgcn_s_barrier();
  __builtin_amdgcn_sched_barrier(0);

  // One pair = K=32: 12 ds_read_b128 + 32 MFMA + 4 staged loads, ONE barrier.
#define PAIR(SLOT, KH, DO_STAGE, TVM)                                             \
  {                                                                               \
    bf16x8 afr[4], bfr[4], afr2[4];                                               \
    _Pragma("unroll") for (int mi = 0; mi < 4; ++mi)                              \
      afr[mi] = *(const bf16x8*)&lds[(SLOT) * 16384 + aoff + mi * 512];           \
    _Pragma("unroll") for (int ni = 0; ni < 4; ++ni)                              \
      bfr[ni] = *(const bf16x8*)&lds[(SLOT) * 16384 + boff + ni * 512];           \
    if (DO_STAGE) STAGE_A(((SLOT) + 3) & 3, (KH) + 3);                            \
    __builtin_amdgcn_s_setprio(1);                                                \
    _Pragma("unroll") for (int mi = 0; mi < 4; ++mi)                              \
      _Pragma("unroll") for (int ni = 0; ni < 4; ++ni)                            \
        acc[mi][ni] = __builtin_amdgcn_mfma_f32_16x16x32_bf16(                    \
            afr[mi], bfr[ni], acc[mi][ni], 0, 0, 0);                              \
    __builtin_amdgcn_s_setprio(0);                                                \
    _Pragma("unroll") for (int mi = 0; mi < 4; ++mi)                              \
      afr2[mi] = *(const bf16x8*)&lds[(SLOT) * 16384 + aoff + (4 + mi) * 512];    \
    if (DO_STAGE) STAGE_B(((SLOT) + 3) & 3, (KH) + 3);                            \
    __builtin_amdgcn_s_setprio(1);                                                \
    _Pragma("unroll") for (int mi = 0; mi < 4; ++mi)                              \
      _Pragma("unroll") for (int ni = 0; ni < 4; ++ni)                            \
        acc[4 + mi][ni] = __builtin_amdgcn_mfma_f32_16x16x32_bf16(                \
            afr2[mi], bfr[ni], acc[4 + mi][ni], 0, 0, 0);                         \
    __builtin_amdgcn_s_setprio(0);                                                \
    asm volatile("s_waitcnt " TVM ::: "memory");                                  \
    __builtin_amdgcn_s_barrier();                                                 \
    __builtin_amdgcn_sched_barrier(0);                                            \
  }

  // Main loop: 31 ring revolutions (pairs 0..123), all staging P_{n+3}.
  for (int kh = 0; kh < 124; kh += 4) {
    PAIR(0, kh + 0, true, "vmcnt(8)");
    PAIR(1, kh + 1, true, "vmcnt(8)");
    PAIR(2, kh + 2, true, "vmcnt(8)");
    PAIR(3, kh + 3, true, "vmcnt(8)");
  }
  // Tail: pair 124 still stages P_127; then drain 8 -> 4 -> 0.
  PAIR(0, 124, true,  "vmcnt(8)");
  PAIR(1, 125, false, "vmcnt(4)");
  PAIR(2, 126, false, "vmcnt(0)");
  PAIR(3, 127, false, "vmcnt(0)");

#undef PAIR
#undef STAGE_A
#undef STAGE_B

  // Epilogue. C/D layout (m89-verified): col = lane&15, row = (lane>>4)*4 + reg.
#pragma unroll
  for (int ni = 0; ni < 4; ++ni) {
    int n = nbase + wc * 64 + ni * 16 + (ln & 15);
    float bv = bias[n];
#pragma unroll
    for (int mi = 0; mi < 8; ++mi) {
      int m0 = mbase + wr * 128 + mi * 16 + (ln >> 4) * 4;
#pragma unroll
      for (int r = 0; r < 4; ++r)
        C[(size_t)(m0 + r) * OUT_F + n] = acc[mi][ni][r] + bv;
    }
  }
}

// ---------------------------------------------------------------------------
extern "C" void kernel_launch(void* const* d_in, const int* in_sizes, int n_in,
                              void* d_out, int out_size, void* d_ws, size_t ws_size,
                              hipStream_t stream) {
  const float* x       = (const float*)d_in[0];  // [4096][4096]
  const int*   qweight = (const int*)d_in[1];    // [11008][4096]
  const float* scales  = (const float*)d_in[2];  // [11008][32]
  const float* zeros   = (const float*)d_in[3];  // [11008][32]
  const float* bias    = (const float*)d_in[4];  // [11008]
  const float* noise   = (const float*)d_in[5];  // [11008][4096]
  float* out = (float*)d_out;                    // [4096][11008]

  // Workspace layout: wn bf16 [OUT_F][IN_F] (90.2 MB), then xb bf16 (33.6 MB).
  bf16* wn = (bf16*)d_ws;
  bf16* xb = (bf16*)((char*)d_ws + (size_t)OUT_F * IN_F * sizeof(bf16));

  // Phase 1: fused dequant+noise+xcast, grid-strided at 8 blocks/CU.
  prep_kernel<<<2048, 256, 0, stream>>>(x, qweight, scales, zeros, noise, wn, xb);

  // Phase 2: 256x256-tile bf16 MFMA GEMM (16x16x32 core, 1 barrier/pair).
  // Grid: (11008/256)*(4096/256) = 43*16 = 688 = 8 XCDs * 86.
  gemm_8ph_kernel<<<dim3(688), 512, 0, stream>>>(xb, wn, bias, out);
}